// Round 2
// baseline (145.368 us; speedup 1.0000x reference)
//
#include <hip/hip_runtime.h>
#include <stdint.h>

#define N_BOXES 6000
#define NT 94            // real tiles of 64
#define NTP 96           // padded tile count (unroll-3 pipeline)
#define NROWS (NTP * 64) // 6144 padded rows
#define CAP 16           // u16 suppression-list entries per row (sentinel 0xFFFF)
#define NCHUNK 94        // ceil(6000/64) chunks for the rank scan
#define IOU_THR 0.5f
#define CONF_THR 0.6f

typedef unsigned long long u64;
typedef unsigned int u32;
typedef unsigned short u16;

// raw barrier: drain LDS only — global loads to registers may stay in flight
#define BAR() asm volatile("s_waitcnt lgkmcnt(0)\n\ts_barrier" ::: "memory")

__device__ __forceinline__ u64 rdlane64(u64 v, int l) {
    unsigned lo = (unsigned)__builtin_amdgcn_readlane((int)(unsigned)v, l);
    unsigned hi = (unsigned)__builtin_amdgcn_readlane((int)(unsigned)(v >> 32), l);
    return ((u64)hi << 32) | lo;
}

// ---- kernel 1: rank-by-count sort (ballot-popcount) + workspace init ------
// scores uniform [0,1) -> raw float bits monotone. key = (~bits<<32)|index:
// ascending u64 == descending score, ties by ascending index (JAX stable argsort).
// R2 rewrite: the old LDS-broadcast rank loop was DS-issue-bound (6000
// wave-uniform ds_read_b64 per CU ~ 15-20 us). Now each wave owns 4 boxes and
// ranks them against per-lane keys built from global scores (L2-resident):
// cnt += popcount(ballot(key < own)). 1 VMEM + ~3 VALU + ~12 SALU per chunk,
// zero LDS, zero barriers.
__global__ void __launch_bounds__(1024) k_sort(const float* __restrict__ scores,
                                               const float4* __restrict__ boxes,
                                               int* __restrict__ sidx,
                                               float4* __restrict__ sboxes,
                                               u32* __restrict__ lists_w,  // lists as u32
                                               int* __restrict__ cnt) {
    const int tid = threadIdx.x;
    const int gtid = blockIdx.x * 1024 + tid;
    // init sparse-list sentinels + slot counters (spread over 96k threads)
    for (int j = gtid; j < NROWS * CAP / 2; j += NT * 1024) lists_w[j] = 0xFFFFFFFFu;
    for (int j = gtid; j < NROWS; j += NT * 1024) cnt[j] = 0;

    const int w = tid >> 6;          // wave 0..15
    const int lane = tid & 63;
    // wave w ranks own boxes blockIdx*64 + w*4 + 0..3
    u64 own[4];
    int ob[4];
#pragma unroll
    for (int q = 0; q < 4; ++q) {
        ob[q] = blockIdx.x * 64 + w * 4 + q;           // wave-uniform
        float s = (ob[q] < N_BOXES) ? scores[ob[q]] : 0.0f;
        own[q] = ((u64)(~__float_as_uint(s)) << 32) | (unsigned)ob[q];
    }
    int rank0 = 0, rank1 = 0, rank2 = 0, rank3 = 0;
#pragma unroll 2
    for (int cb = 0; cb < NCHUNK; ++cb) {
        int j = cb * 64 + lane;
        u64 kk = ~0ull;                                // pad: never < own
        if (j < N_BOXES) {
            unsigned inv = ~__float_as_uint(scores[j]);
            kk = ((u64)inv << 32) | (unsigned)j;
        }
        rank0 += __popcll(__ballot(kk < own[0]));
        rank1 += __popcll(__ballot(kk < own[1]));
        rank2 += __popcll(__ballot(kk < own[2]));
        rank3 += __popcll(__ballot(kk < own[3]));
    }
    if (lane == 0) {
        int r[4] = {rank0, rank1, rank2, rank3};
#pragma unroll
        for (int q = 0; q < 4; ++q)
            if (ob[q] < N_BOXES) {
                sidx[r[q]] = ob[q];                    // keys distinct -> permutation
                sboxes[r[q]] = boxes[ob[q]];
            }
    }
}

// ---- kernel 2: pairwise IoU -> SPARSE suppression lists + diag words ------
// In-tile (diagonal-block) edges go ONLY to diagw — k_scan's resolve handles
// them — so scatter in k_scan never touches removed[T] during tile T.
// R2: triangular linearized launch (4465 blocks) instead of 94x94 grid with
// half the blocks exiting at ct<rt.
__global__ void k_mask(const float4* __restrict__ sboxes,
                       u16* __restrict__ lists, int* __restrict__ cnt,
                       u64* __restrict__ diagw) {
    const int b = blockIdx.x;
    int v = (int)((sqrtf(8.0f * (float)b + 1.0f) - 1.0f) * 0.5f);
    while ((v + 1) * (v + 2) / 2 <= b) ++v;
    while (v * (v + 1) / 2 > b) --v;
    const int rt = b - v * (v + 1) / 2;   // 0..v  (row tile)
    const int ct = v;                     // col tile, ct >= rt guaranteed
    int lane = threadIdx.x;
    __shared__ float4 rb[64];
    int row0 = rt * 64;
    int rows = min(64, N_BOXES - row0);
    if (lane < rows) rb[lane] = sboxes[row0 + lane];
    __syncthreads();
    int j = ct * 64 + lane;
    bool jvalid = (j < N_BOXES);
    float4 cb = make_float4(0.f, 0.f, 1.f, 1.f);
    if (jvalid) cb = sboxes[j];
    float carea = (cb.z - cb.x) * (cb.w - cb.y);
    bool isdiag = (ct == rt);
    for (int i = 0; i < rows; ++i) {
        float4 rbx = rb[i];
        float rarea = (rbx.z - rbx.x) * (rbx.w - rbx.y);
        // identical f32 op order as the reference (_pairwise_iou)
        float iw = fmaxf(fminf(rbx.z, cb.z) - fmaxf(rbx.x, cb.x), 0.f);
        float ih = fmaxf(fminf(rbx.w, cb.w) - fmaxf(rbx.y, cb.y), 0.f);
        float inter = iw * ih;
        float iou = inter / ((rarea + carea) - inter);
        int row = row0 + i;
        bool pred = jvalid && (j > row) && (iou > IOU_THR);
        if (isdiag) {
            u64 bal = __ballot(pred);
            if (lane == (i & 63)) diagw[row] = bal;
        } else if (pred) {           // cross-tile edges only (~rare)
            int slot = atomicAdd(&cnt[row], 1);
            if (slot < CAP) lists[row * CAP + slot] = (u16)j;
        }
    }
}

// ---- kernel 3: greedy scan — 4 waves, distance-3 prefetch, CAP=16 ---------
// (R2: reverted to the R0 4-wave lockstep version — measured 44.8-45.6 us.
// R1's single-wave/zero-barrier variant regressed to 53.6 us: with one wave
// there is no TLP, so every exposed latency lands on the serial chain.)
// 256 threads: row_l = tid>>2 (4 threads/row), each holds 4 u16 entries (8B).
// 3 rotating buffers, loads issued 3 tiles (~900 cyc) before consumption —
// covers remote-XCD/HBM latency. All 4 waves redundantly resolve (identical
// diag registers), so kw is register-resident everywhere; 1 barrier/tile.
// Pad tiles 94,95: valid=0 -> kw=0 -> no scatter (diag garbage harmless).
__global__ void __launch_bounds__(256) k_scan(const u16* __restrict__ lists,
                                              const u64* __restrict__ diagw,
                                              const int* __restrict__ sidx,
                                              const float* __restrict__ scores,
                                              float* __restrict__ out) {
    __shared__ u64 removed[NTP];
    __shared__ u64 kwbuf[NTP];
    const int tid   = threadIdx.x;
    const int lane  = tid & 63;
    const int row_l = tid >> 2;              // local row 0..63
    const int sg    = (tid & 3) * 4;         // entry-group start (4 u16 = 8 B)
    if (tid < NTP) removed[tid] = 0;

    u64 L0, L1, L2, D0, D1, D2;
    L0 = *(const u64*)&lists[(0 * 64 + row_l) * CAP + sg];
    L1 = *(const u64*)&lists[(1 * 64 + row_l) * CAP + sg];
    L2 = *(const u64*)&lists[(2 * 64 + row_l) * CAP + sg];
    D0 = diagw[0 * 64 + lane];
    D1 = diagw[1 * 64 + lane];
    D2 = diagw[2 * 64 + lane];
    __syncthreads();   // full barrier once (covers removed[] init)

#define STEP(T, LUSE, DUSE)                                                    \
    {                                                                          \
        const u64 nz = __ballot(DUSE != 0ull);   /* in-tile suppressors */     \
        const int row0 = (T) * 64;                                             \
        const int rem = N_BOXES - row0;                                        \
        const u64 valid = (rem >= 64) ? ~0ull                                  \
                        : ((rem <= 0) ? 0ull : ((1ull << rem) - 1ull));        \
        u64 c = valid & ~removed[(T)];                                         \
        u64 kw = 0;                                                            \
        while (c) {                                                            \
            u64 blockers = c & nz;                                             \
            if (!blockers) { kw |= c; break; }     /* bulk-keep rest */        \
            int g = (int)__builtin_ctzll(blockers);                            \
            u64 below = c & ((1ull << g) - 1ull);  /* zero-diag: kept */       \
            kw |= below | (1ull << g);                                         \
            u64 df = rdlane64(DUSE, g);            /* bits > g only */         \
            c &= ~(df | below | (1ull << g));                                  \
        }                                                                      \
        if (tid == 0) kwbuf[(T)] = kw;                                         \
        if (((kw >> row_l) & 1ull) && LUSE != ~0ull) {                         \
            u16 e0 = (u16)(LUSE), e1 = (u16)(LUSE >> 16),                      \
                e2 = (u16)(LUSE >> 32), e3 = (u16)(LUSE >> 48);                \
            if (e0 != 0xFFFFu) atomicOr(&removed[e0 >> 6], 1ull << (e0 & 63)); \
            if (e1 != 0xFFFFu) atomicOr(&removed[e1 >> 6], 1ull << (e1 & 63)); \
            if (e2 != 0xFFFFu) atomicOr(&removed[e2 >> 6], 1ull << (e2 & 63)); \
            if (e3 != 0xFFFFu) atomicOr(&removed[e3 >> 6], 1ull << (e3 & 63)); \
        }                                                                      \
        const int tn = ((T) + 3 < NTP) ? ((T) + 3) : ((T) + 3 - NTP);          \
        LUSE = *(const u64*)&lists[(tn * 64 + row_l) * CAP + sg];              \
        DUSE = diagw[tn * 64 + lane];                                          \
        BAR();                                                                 \
    }

    for (int t = 0; t < NTP; t += 3) {       // NTP = 96 = 32 x 3
        STEP(t,     L0, D0)
        STEP(t + 1, L1, D1)
        STEP(t + 2, L2, D2)
    }
#undef STEP

    // ---- epilogue: masked scores through the sort permutation ----
    for (int p = tid; p < N_BOXES; p += 256) {
        int orig = sidx[p];
        float s = scores[orig];
        bool k = (kwbuf[p >> 6] >> (p & 63)) & 1ull;
        out[orig] = (k && (s >= CONF_THR)) ? s : 0.0f;  // writes ALL outputs
    }
}

extern "C" void kernel_launch(void* const* d_in, const int* in_sizes, int n_in,
                              void* d_out, int out_size, void* d_ws, size_t ws_size,
                              hipStream_t stream) {
    const float* boxes  = (const float*)d_in[0];    // [6000,4]
    const float* scores = (const float*)d_in[1];    // [6000]
    float* out = (float*)d_out;                     // [6000]

    // workspace layout
    char* ws = (char*)d_ws;
    u16*    lists  = (u16*)(ws);                    // 6144*16*2 = 196,608 B
    int*    cnt    = (int*)(ws + 196608);           // 6144*4    =  24,576 B
    u64*    diagw  = (u64*)(ws + 221184);           // 96*64*8   =  49,152 B
    int*    sidx   = (int*)(ws + 270336);           // 24,000 B
    float4* sboxes = (float4*)(ws + 294336);        // 96,000 B (16B aligned)

    k_sort<<<dim3(NT), dim3(1024), 0, stream>>>(scores, (const float4*)boxes, sidx,
                                                sboxes, (u32*)lists, cnt);
    k_mask<<<dim3(NT * (NT + 1) / 2), dim3(64), 0, stream>>>((const float4*)sboxes,
                                                             lists, cnt, diagw);
    k_scan<<<dim3(1), dim3(256), 0, stream>>>(lists, diagw, sidx, scores, out);
}

// Round 3
// 136.066 us; speedup vs baseline: 1.0684x; 1.0684x over previous
//
#include <hip/hip_runtime.h>
#include <stdint.h>

#define N_BOXES 6000
#define NT 94            // real tiles of 64
#define NTP 96           // padded tile count (unroll-3 pipeline)
#define NROWS (NTP * 64) // 6144 padded rows
#define CAP 16           // u16 suppression-list entries per row (sentinel 0xFFFF)
#define IOU_THR 0.5f
#define CONF_THR 0.6f

typedef unsigned long long u64;
typedef unsigned int u32;
typedef unsigned short u16;

// raw barrier: drain LDS only — global loads to registers may stay in flight
#define BAR() asm volatile("s_waitcnt lgkmcnt(0)\n\ts_barrier" ::: "memory")

__device__ __forceinline__ u64 rdlane64(u64 v, int l) {
    unsigned lo = (unsigned)__builtin_amdgcn_readlane((int)(unsigned)v, l);
    unsigned hi = (unsigned)__builtin_amdgcn_readlane((int)(unsigned)(v >> 32), l);
    return ((u64)hi << 32) | lo;
}

// ---- kernel 1: fused sort (keys + rank + scatter) + workspace init --------
// (R3: reverted to the R0 LDS-broadcast version. R2's ballot-popcount rewrite
// regressed ~13 us total: per-wave 94-chunk load->ballot chain serializes on
// wave-wide load latency at 1 block/CU TLP; the LDS version amortizes one
// staging pass across 16 waves.)
// scores uniform [0,1) -> raw float bits monotone. key = (~bits<<32)|index:
// ascending u64 == descending score, ties by ascending index (JAX stable argsort).
__global__ void __launch_bounds__(1024) k_sort(const float* __restrict__ scores,
                                               const float4* __restrict__ boxes,
                                               int* __restrict__ sidx,
                                               float4* __restrict__ sboxes,
                                               u32* __restrict__ lists_w,  // lists as u32
                                               int* __restrict__ cnt) {
    __shared__ u64 kt[N_BOXES];      // 48,000 B
    __shared__ int part[1024];
    const int tid = threadIdx.x;
    const int gtid = blockIdx.x * 1024 + tid;
    // init sparse-list sentinels + slot counters (spread over 96k threads)
    for (int j = gtid; j < NROWS * CAP / 2; j += NT * 1024) lists_w[j] = 0xFFFFFFFFu;
    for (int j = gtid; j < NROWS; j += NT * 1024) cnt[j] = 0;

    for (int j = tid; j < N_BOXES; j += 1024) {
        unsigned inv = ~__float_as_uint(scores[j]);
        kt[j] = ((u64)inv << 32) | (unsigned)j;
    }
    __syncthreads();
    const int il = tid & 63;
    const int i = blockIdx.x * 64 + il;
    const int j0 = (tid >> 6) * 375;         // 16 segments of 375 (wave-uniform)
    u64 mykey = (i < N_BOXES) ? kt[i] : 0ull;
    int cntr = 0;
#pragma unroll 5
    for (int jj = 0; jj < 375; ++jj)
        cntr += (kt[j0 + jj] < mykey) ? 1 : 0;
    part[tid] = cntr;
    __syncthreads();
    if (tid < 64 && i < N_BOXES) {
        int r = 0;
#pragma unroll
        for (int s = 0; s < 16; ++s) r += part[il + 64 * s];
        sidx[r] = i;                 // keys distinct -> permutation
        sboxes[r] = boxes[i];
    }
}

// ---- kernel 2: pairwise IoU -> SPARSE suppression lists + diag words ------
// (R3: reverted to the R0 2D early-exit grid — R2's triangular launch was
// part of a +13 us confounded regression; re-anchoring on the known-good.)
// In-tile (diagonal-block) edges go ONLY to diagw — k_scan's resolve handles
// them — so scatter in k_scan never touches removed[T] during tile T.
__global__ void k_mask(const float4* __restrict__ sboxes,
                       u16* __restrict__ lists, int* __restrict__ cnt,
                       u64* __restrict__ diagw) {
    int ct = blockIdx.x, rt = blockIdx.y;
    if (ct < rt) return;
    int lane = threadIdx.x;
    __shared__ float4 rb[64];
    int row0 = rt * 64;
    int rows = min(64, N_BOXES - row0);
    if (lane < rows) rb[lane] = sboxes[row0 + lane];
    __syncthreads();
    int j = ct * 64 + lane;
    bool jvalid = (j < N_BOXES);
    float4 cb = make_float4(0.f, 0.f, 1.f, 1.f);
    if (jvalid) cb = sboxes[j];
    float carea = (cb.z - cb.x) * (cb.w - cb.y);
    bool isdiag = (ct == rt);
    for (int i = 0; i < rows; ++i) {
        float4 rbx = rb[i];
        float rarea = (rbx.z - rbx.x) * (rbx.w - rbx.y);
        // identical f32 op order as the reference (_pairwise_iou)
        float iw = fmaxf(fminf(rbx.z, cb.z) - fmaxf(rbx.x, cb.x), 0.f);
        float ih = fmaxf(fminf(rbx.w, cb.w) - fmaxf(rbx.y, cb.y), 0.f);
        float inter = iw * ih;
        float iou = inter / ((rarea + carea) - inter);
        int row = row0 + i;
        bool pred = jvalid && (j > row) && (iou > IOU_THR);
        if (isdiag) {
            u64 bal = __ballot(pred);
            if (lane == (i & 63)) diagw[row] = bal;
        } else if (pred) {           // cross-tile edges only (~rare)
            int slot = atomicAdd(&cnt[row], 1);
            if (slot < CAP) lists[row * CAP + slot] = (u16)j;
        }
    }
}

// ---- kernel 3: greedy scan — 4 waves, distance-3 prefetch, CAP=16 ---------
// 256 threads: row_l = tid>>2 (4 threads/row), each holds 4 u16 entries (8B).
// 3 rotating buffers, loads issued 3 tiles (~900 cyc) before consumption —
// covers remote-XCD/HBM latency. All 4 waves redundantly resolve (identical
// diag registers), so kw is register-resident everywhere; 1 barrier/tile.
// Pad tiles 94,95: valid=0 -> kw=0 -> no scatter (diag garbage harmless).
// R3 change: kw no longer written to LDS per tile (the tid0 ds_write was
// issued only after kw finalized, and BAR's lgkmcnt(0) drained it — ~80-100
// serial cyc x 96 tiles). Lane L of each wave captures tile L's kw in a
// register (2 cndmask_b64/tile); wave 0 dumps all 96 words to kwbuf once
// after the loop. BAR's drain now only covers the rare scatter ds_or.
__global__ void __launch_bounds__(256) k_scan(const u16* __restrict__ lists,
                                              const u64* __restrict__ diagw,
                                              const int* __restrict__ sidx,
                                              const float* __restrict__ scores,
                                              float* __restrict__ out) {
    __shared__ u64 removed[NTP];
    __shared__ u64 kwbuf[NTP];
    const int tid   = threadIdx.x;
    const int lane  = tid & 63;
    const int row_l = tid >> 2;              // local row 0..63
    const int sg    = (tid & 3) * 4;         // entry-group start (4 u16 = 8 B)
    if (tid < NTP) removed[tid] = 0;

    u64 L0, L1, L2, D0, D1, D2;
    L0 = *(const u64*)&lists[(0 * 64 + row_l) * CAP + sg];
    L1 = *(const u64*)&lists[(1 * 64 + row_l) * CAP + sg];
    L2 = *(const u64*)&lists[(2 * 64 + row_l) * CAP + sg];
    D0 = diagw[0 * 64 + lane];
    D1 = diagw[1 * 64 + lane];
    D2 = diagw[2 * 64 + lane];
    u64 kw0 = 0, kw1 = 0;                    // lane-resident kw capture
    __syncthreads();   // full barrier once (covers removed[] init)

#define STEP(T, LUSE, DUSE)                                                    \
    {                                                                          \
        const u64 nz = __ballot(DUSE != 0ull);   /* in-tile suppressors */     \
        const int row0 = (T) * 64;                                             \
        const int rem = N_BOXES - row0;                                        \
        const u64 valid = (rem >= 64) ? ~0ull                                  \
                        : ((rem <= 0) ? 0ull : ((1ull << rem) - 1ull));        \
        u64 c = valid & ~removed[(T)];                                         \
        u64 kw = 0;                                                            \
        while (c) {                                                            \
            u64 blockers = c & nz;                                             \
            if (!blockers) { kw |= c; break; }     /* bulk-keep rest */        \
            int g = (int)__builtin_ctzll(blockers);                            \
            u64 below = c & ((1ull << g) - 1ull);  /* zero-diag: kept */       \
            kw |= below | (1ull << g);                                         \
            u64 df = rdlane64(DUSE, g);            /* bits > g only */         \
            c &= ~(df | below | (1ull << g));                                  \
        }                                                                      \
        kw0 = (lane == (T)) ? kw : kw0;          /* tile L -> lane L (T<64) */ \
        kw1 = (lane == (T) - 64) ? kw : kw1;     /* tile 64+L -> lane L */     \
        if (((kw >> row_l) & 1ull) && LUSE != ~0ull) {                         \
            u16 e0 = (u16)(LUSE), e1 = (u16)(LUSE >> 16),                      \
                e2 = (u16)(LUSE >> 32), e3 = (u16)(LUSE >> 48);                \
            if (e0 != 0xFFFFu) atomicOr(&removed[e0 >> 6], 1ull << (e0 & 63)); \
            if (e1 != 0xFFFFu) atomicOr(&removed[e1 >> 6], 1ull << (e1 & 63)); \
            if (e2 != 0xFFFFu) atomicOr(&removed[e2 >> 6], 1ull << (e2 & 63)); \
            if (e3 != 0xFFFFu) atomicOr(&removed[e3 >> 6], 1ull << (e3 & 63)); \
        }                                                                      \
        const int tn = ((T) + 3 < NTP) ? ((T) + 3) : ((T) + 3 - NTP);          \
        LUSE = *(const u64*)&lists[(tn * 64 + row_l) * CAP + sg];              \
        DUSE = diagw[tn * 64 + lane];                                          \
        BAR();                                                                 \
    }

    for (int t = 0; t < NTP; t += 3) {       // NTP = 96 = 32 x 3
        STEP(t,     L0, D0)
        STEP(t + 1, L1, D1)
        STEP(t + 2, L2, D2)
    }
#undef STEP

    // wave 0 publishes the register-resident kw words once
    if (tid < 64) kwbuf[tid] = kw0;
    if (tid < 32) kwbuf[64 + tid] = kw1;
    __syncthreads();

    // ---- epilogue: masked scores through the sort permutation ----
    for (int p = tid; p < N_BOXES; p += 256) {
        int orig = sidx[p];
        float s = scores[orig];
        bool k = (kwbuf[p >> 6] >> (p & 63)) & 1ull;
        out[orig] = (k && (s >= CONF_THR)) ? s : 0.0f;  // writes ALL outputs
    }
}

extern "C" void kernel_launch(void* const* d_in, const int* in_sizes, int n_in,
                              void* d_out, int out_size, void* d_ws, size_t ws_size,
                              hipStream_t stream) {
    const float* boxes  = (const float*)d_in[0];    // [6000,4]
    const float* scores = (const float*)d_in[1];    // [6000]
    float* out = (float*)d_out;                     // [6000]

    // workspace layout
    char* ws = (char*)d_ws;
    u16*    lists  = (u16*)(ws);                    // 6144*16*2 = 196,608 B
    int*    cnt    = (int*)(ws + 196608);           // 6144*4    =  24,576 B
    u64*    diagw  = (u64*)(ws + 221184);           // 96*64*8   =  49,152 B
    int*    sidx   = (int*)(ws + 270336);           // 24,000 B
    float4* sboxes = (float4*)(ws + 294336);        // 96,000 B (16B aligned)

    k_sort<<<dim3(NT), dim3(1024), 0, stream>>>(scores, (const float4*)boxes, sidx,
                                                sboxes, (u32*)lists, cnt);
    k_mask<<<dim3(NT, NT), dim3(64), 0, stream>>>((const float4*)sboxes, lists, cnt, diagw);
    k_scan<<<dim3(1), dim3(256), 0, stream>>>(lists, diagw, sidx, scores, out);
}